// Round 5
// baseline (565.565 us; speedup 1.0000x reference)
//
#include <hip/hip_runtime.h>

// Problem constants (N=8192 tokens, D=256 model dim, dropout p=0.5 -> keep scale 2.0)
#define NT 8192
#define DM 256

typedef float f32x16 __attribute__((ext_vector_type(16)));
typedef __bf16 bf16x8 __attribute__((ext_vector_type(8)));
typedef unsigned int u32x4 __attribute__((ext_vector_type(4)));

#define MFMA32(a, b, c) __builtin_amdgcn_mfma_f32_32x32x16_bf16((a), (b), (c), 0, 0, 0)
#define NEG_INF (-__builtin_inff())

static __device__ __forceinline__ unsigned short f2bf_bits(float f) {
  return __builtin_bit_cast(unsigned short, (__bf16)f);
}
static __device__ __forceinline__ float exp2_fast(float x) {
  return __builtin_amdgcn_exp2f(x);
}
// async global->LDS, 16B per lane. LDS dest is wave-uniform base + lane*16.
static __device__ __forceinline__ void gload_lds16(const void* g, void* l) {
  __builtin_amdgcn_global_load_lds(
      (const __attribute__((address_space(1))) unsigned int*)g,
      (__attribute__((address_space(3))) unsigned int*)l, 16, 0, 0);
}

// ---------------------------------------------------------------------------
// Kernel 0: classify drop_mask storage. 1 = int32 {0,1}, 2 = float32 {0,1.0f},
// 0 = uint8 bytes. Scans first 256 dwords. (Only element size matters below.)
// ---------------------------------------------------------------------------
__global__ void detect_kernel(const unsigned int* __restrict__ m, int* __restrict__ flag) {
  __shared__ int s01, sf;
  int t = threadIdx.x;
  if (t == 0) { s01 = 1; sf = 1; }
  __syncthreads();
  unsigned int v = m[t];
  if (v > 1u) atomicAnd(&s01, 0);
  if (v != 0u && v != 0x3F800000u) atomicAnd(&sf, 0);
  __syncthreads();
  if (t == 0) *flag = s01 ? 1 : (sf ? 2 : 0);
}

// ---------------------------------------------------------------------------
// Kernel 0b: compress drop_mask (lower triangle only) into a bitmask,
// bm[i] = 8192 bits (128 u64 words). Pure streaming, ballot-based.
// ---------------------------------------------------------------------------
__global__ __launch_bounds__(256) void maskpack_kernel(
    const void* __restrict__ mask, const int* __restrict__ flagp,
    unsigned long long* __restrict__ bm) {
  const int t = threadIdx.x, lane = t & 63, w = t >> 6;
  const int r = blockIdx.x + (w << 11);  // grid 2048 -> rows r, r+2048, ...
  const int mode = *flagp;               // 0 = 1-byte elements, else 4-byte
  const int jmax = ((r >> 6) + 1) << 6;  // cover cols 0..r (round up to 64)
  unsigned long long* out = bm + (size_t)r * 128;
  if (mode == 0) {
    const unsigned char* mk = (const unsigned char*)mask + (size_t)r * NT;
    for (int j = 0; j < jmax; j += 64) {
      unsigned long long b = __ballot(mk[j + lane] != 0);
      if (lane == 0) out[j >> 6] = b;
    }
  } else {
    const unsigned int* mk = (const unsigned int*)mask + (size_t)r * NT;
    for (int j = 0; j < jmax; j += 64) {
      unsigned long long b = __ballot(mk[j + lane] != 0u);
      if (lane == 0) out[j >> 6] = b;
    }
  }
}

// ---------------------------------------------------------------------------
// Kernel 1: QKV projection. X[8192][256] f32, W[256][256] f32 (torch layout,
// out = X @ W^T). Outputs bf16: Qs (pre-scaled by log2(e)/16), K, and V stored
// transposed Vt[256][8192] PRE-SCALED by 2.0 (dropout keep-scale folded in).
// grid (128 row-blocks, 3 mats), block 256.
// ---------------------------------------------------------------------------
__global__ __launch_bounds__(256) void proj_kernel(
    const float* __restrict__ X, const float* __restrict__ Wq,
    const float* __restrict__ Wk, const float* __restrict__ Wv,
    unsigned short* __restrict__ Qs, unsigned short* __restrict__ Kb,
    unsigned short* __restrict__ Vt) {
  __shared__ __align__(16) unsigned short Xs[64 * 256];
  __shared__ __align__(16) unsigned short Ws[64 * 256];
  __shared__ float Tr[4][32 * 33];
  const int ib = blockIdx.x, mat = blockIdx.y;
  const float* W = (mat == 0) ? Wq : (mat == 1) ? Wk : Wv;
  // mat 0: fold softmax scale (1/sqrt(256)) and log2(e); mat 2: fold dropout 2x
  const float wscale = (mat == 0) ? 0.09016844005556021f : (mat == 2 ? 2.0f : 1.0f);
  const int t = threadIdx.x;
  const int lane = t & 63, w = t >> 6;
  const int m = lane & 31, half = lane >> 5;
  const int i0 = ib * 64;
#pragma unroll
  for (int cc = 0; cc < 8; ++cc) {
    int chunk = t + 256 * cc;
    int rr = chunk >> 5, c = chunk & 31;
    const float4* src = (const float4*)(X + (size_t)(i0 + rr) * 256 + c * 8);
    float4 f0 = src[0], f1 = src[1];
    bf16x8 v;
    v[0] = (__bf16)f0.x; v[1] = (__bf16)f0.y; v[2] = (__bf16)f0.z; v[3] = (__bf16)f0.w;
    v[4] = (__bf16)f1.x; v[5] = (__bf16)f1.y; v[6] = (__bf16)f1.z; v[7] = (__bf16)f1.w;
    *(bf16x8*)&Xs[(rr * 32 + (c ^ (rr & 31))) * 8] = v;
  }
  const int wr = w >> 1, wc = w & 1;
  for (int cb = 0; cb < 4; ++cb) {
    __syncthreads();
#pragma unroll
    for (int cc = 0; cc < 8; ++cc) {
      int chunk = t + 256 * cc;
      int rr = chunk >> 5, c = chunk & 31;
      const float4* src = (const float4*)(W + (size_t)(cb * 64 + rr) * 256 + c * 8);
      float4 f0 = src[0], f1 = src[1];
      bf16x8 v;
      v[0] = (__bf16)(f0.x * wscale); v[1] = (__bf16)(f0.y * wscale);
      v[2] = (__bf16)(f0.z * wscale); v[3] = (__bf16)(f0.w * wscale);
      v[4] = (__bf16)(f1.x * wscale); v[5] = (__bf16)(f1.y * wscale);
      v[6] = (__bf16)(f1.z * wscale); v[7] = (__bf16)(f1.w * wscale);
      *(bf16x8*)&Ws[(rr * 32 + (c ^ (rr & 31))) * 8] = v;
    }
    __syncthreads();
    f32x16 acc = {};
    const int ar = 32 * wr + m;
    const int br = 32 * wc + m;
#pragma unroll
    for (int st = 0; st < 16; ++st) {
      int kc = st * 2 + half;
      bf16x8 a = *(const bf16x8*)&Xs[(ar * 32 + (kc ^ (ar & 31))) * 8];
      bf16x8 b = *(const bf16x8*)&Ws[(br * 32 + (kc ^ (br & 31))) * 8];
      acc = MFMA32(a, b, acc);
    }
    if (mat < 2) {
      unsigned short* O = mat ? Kb : Qs;
#pragma unroll
      for (int r = 0; r < 16; ++r) {
        int row = i0 + 32 * wr + (r & 3) + 8 * (r >> 2) + 4 * half;
        int col = cb * 64 + 32 * wc + m;
        O[(size_t)row * DM + col] = f2bf_bits(acc[r]);
      }
    } else {
      float* T = Tr[w];
#pragma unroll
      for (int r = 0; r < 16; ++r) {
        int rl = (r & 3) + 8 * (r >> 2) + 4 * half;
        T[m * 33 + rl] = acc[r];
      }
      asm volatile("s_waitcnt lgkmcnt(0)" ::: "memory");
#pragma unroll
      for (int q = 0; q < 16; ++q) {
        int dl = 2 * q + half;
        float val = T[dl * 33 + m];
        Vt[(size_t)(cb * 64 + 32 * wc + dl) * NT + i0 + 32 * wr + m] = f2bf_bits(val);
      }
      asm volatile("s_waitcnt lgkmcnt(0)" ::: "memory");
    }
  }
}

// ---------------------------------------------------------------------------
// Kernel 2: flash attention, causal, post-softmax dropout (x2 folded into Vt).
// v5: 32-row waves with MFMA32 in transposed layout (S^T = K Q^T,
// O^T = V^T P^T). Lane owns one query row (i = lane&31, both halves).
// - K/V fragment LDS reads amortized over 32 rows (2x vs v4's 16).
// - P LDS round-trip eliminated: S^T D-layout -> PV B-frag needs only a
//   32-lane half swap (4 shfl_xor).
// - Race-free dbuf: barrier1 (prev compute done) -> issue next DMA ->
//   vmcnt(8) (own tile landed) -> barrier2 (all tiles landed) -> compute.
//   Prefetch stays in flight across both barriers.
// BM=128 (4 waves x 32 rows), BN=32, LDS 64 KiB -> 2 blocks/CU.
// MFMA32 layout: A[m=lane&31][k=8h+j], B[k=8h+j][n=lane&31],
//   D reg r: m=(r&3)+8*(r>>2)+4h, n=lane&31.
// ---------------------------------------------------------------------------
__global__ __launch_bounds__(256, 2) void flash_kernel(
    const unsigned short* __restrict__ Qs, const unsigned short* __restrict__ Kg,
    const unsigned short* __restrict__ Vtg, const unsigned int* __restrict__ bm,
    float* __restrict__ ml_out, unsigned short* __restrict__ acc_out) {
  __shared__ __align__(16) unsigned short Ksh[2][32 * 256];  // 2 x 16 KiB
  __shared__ __align__(16) unsigned short Vsh[2][256 * 32];  // 2 x 16 KiB
  const int ib = blockIdx.x, seg = blockIdx.y;
  const int jb_end = 4 * (ib + 1);      // 32-col tiles covering rows..diag
  const int jb0 = seg * 16;
  if (jb0 >= jb_end) return;
  const int jb1 = (jb0 + 16 < jb_end) ? jb0 + 16 : jb_end;
  const int t = threadIdx.x, lane = t & 63, w = t >> 6;
  const int il = lane & 31, h = lane >> 5;
  const int i0 = ib * 128, rw0 = i0 + 32 * w;
  const int myrow = rw0 + il;

  // Q B-fragments, register resident: Q[myrow][16*st + 8h + 0..7], 64 VGPRs
  bf16x8 qf[16];
  {
    const unsigned short* qp = Qs + (size_t)myrow * DM + 8 * h;
#pragma unroll
    for (int st = 0; st < 16; ++st) qf[st] = *(const bf16x8*)(qp + st * 16);
  }
  f32x16 oacc[8] = {};   // O^T: d = ct*32 + (r&3)+8*(r>>2)+4h, col = myrow
  float mrun = -1e30f, lrun = 0.f;

#define STAGE(JB, B)                                                          \
  {                                                                           \
    const int j32_ = (JB) * 32;                                               \
    _Pragma("unroll") for (int i_ = 0; i_ < 4; ++i_) {                        \
      int chunk = t + 256 * i_;                                               \
      int row = chunk >> 5, slot = chunk & 31;                                \
      gload_lds16(Kg + (size_t)(j32_ + row) * DM + (slot ^ row) * 8,          \
                  &Ksh[B][(size_t)chunk * 8]);                                \
    }                                                                         \
    _Pragma("unroll") for (int i_ = 0; i_ < 4; ++i_) {                        \
      int chunk = t + 256 * i_;                                               \
      int d_ = chunk >> 2, slot = chunk & 3;                                  \
      gload_lds16(Vtg + (size_t)d_ * NT + j32_ + (slot ^ ((d_ >> 1) & 3)) * 8,\
                  &Vsh[B][(size_t)chunk * 8]);                                \
    }                                                                         \
  }

  STAGE(jb0, 0)
  for (int jb = jb0; jb < jb1; ++jb) {
    const int buf = (jb - jb0) & 1;
    const int j32 = jb * 32;
    // barrier 1: every wave done computing tile jb-1 -> buf^1 free to overwrite
    __builtin_amdgcn_s_barrier();
    unsigned int bits = bm[(size_t)myrow * 256 + (j32 >> 5)];
    if (jb + 1 < jb1) {
      STAGE(jb + 1, buf ^ 1)
      // drain own tile-jb loads (+bits); keep tile jb+1's 8 in flight
      asm volatile("s_waitcnt vmcnt(8)" ::: "memory");
    } else {
      asm volatile("s_waitcnt vmcnt(0)" ::: "memory");
    }
    // barrier 2: all waves drained their tile-jb loads -> LDS tile complete
    __builtin_amdgcn_s_barrier();
    if (j32 <= rw0 + 31) {
      const unsigned short* Kb_ = Ksh[buf];
      const unsigned short* Vb_ = Vsh[buf];
      // S^T = K Q^T: one 32x32 j-tile, K=256 -> 16 MFMA32
      f32x16 s = {};
#pragma unroll
      for (int st = 0; st < 16; ++st) {
        int c = (2 * st + h) ^ il;
        bf16x8 a = *(const bf16x8*)&Kb_[(il * 32 + c) * 8];
        s = MFMA32(a, qf[st], s);
      }
      // causal mask: reg r holds j = j32 + (r&3)+8*(r>>2)+4h, row = myrow
      if (j32 + 31 > myrow) {
#pragma unroll
        for (int r = 0; r < 16; ++r) {
          int J = (r & 3) + 8 * (r >> 2) + 4 * h;
          if (j32 + J > myrow) s[r] = NEG_INF;
        }
      }
      // online softmax: row = lane's il (scalar state); reduce 16 regs + half swap
      float mx = s[0];
#pragma unroll
      for (int r = 1; r < 16; ++r) mx = fmaxf(mx, s[r]);
      mx = fmaxf(mx, __shfl_xor(mx, 32));
      const float mn = fmaxf(mrun, mx);
#pragma unroll
      for (int r = 0; r < 16; ++r) s[r] = exp2_fast(s[r] - mn);
      float rs = 0.f;
#pragma unroll
      for (int r = 0; r < 16; ++r) rs += s[r];
      rs += __shfl_xor(rs, 32);
      if (__all(mn == mrun)) {
        lrun += rs;                  // running max unchanged: skip O rescale
      } else {
        float alpha = exp2_fast(mrun - mn);
        lrun = lrun * alpha + rs;
#pragma unroll
        for (int ct = 0; ct < 8; ++ct)
#pragma unroll
          for (int r = 0; r < 16; ++r) oacc[ct][r] *= alpha;
        mrun = mn;
      }
      // dropout (zero-only; 2x is in Vt) + pack to bf16 dwords.
      // reg 4t+p holds j = 8t+4h+p -> dword d[2t+(p>>1)] = pair J2 = 4t+2h+(p>>1)
      unsigned int dw[8];
#pragma unroll
      for (int tt = 0; tt < 4; ++tt) {
        unsigned int bb = bits >> (8 * tt + 4 * h);
        float v0 = (bb & 1u) ? s[4 * tt + 0] : 0.f;
        float v1 = (bb & 2u) ? s[4 * tt + 1] : 0.f;
        float v2 = (bb & 4u) ? s[4 * tt + 2] : 0.f;
        float v3 = (bb & 8u) ? s[4 * tt + 3] : 0.f;
        dw[2 * tt] = (unsigned)f2bf_bits(v0) | ((unsigned)f2bf_bits(v1) << 16);
        dw[2 * tt + 1] = (unsigned)f2bf_bits(v2) | ((unsigned)f2bf_bits(v3) << 16);
      }
      // build P^T B-frags: lane needs P[myrow][16kk + 8h + 0..7] -> half swap
      unsigned int x0 = __shfl_xor(h ? dw[0] : dw[2], 32);
      unsigned int x1 = __shfl_xor(h ? dw[1] : dw[3], 32);
      unsigned int x2 = __shfl_xor(h ? dw[4] : dw[6], 32);
      unsigned int x3 = __shfl_xor(h ? dw[5] : dw[7], 32);
      u32x4 pw0, pw1;
      if (h == 0) {
        pw0 = (u32x4){dw[0], dw[1], x0, x1};
        pw1 = (u32x4){dw[4], dw[5], x2, x3};
      } else {
        pw0 = (u32x4){x0, x1, dw[2], dw[3]};
        pw1 = (u32x4){x2, x3, dw[6], dw[7]};
      }
      bf16x8 pf0 = __builtin_bit_cast(bf16x8, pw0);
      bf16x8 pf1 = __builtin_bit_cast(bf16x8, pw1);
      // O^T += V^T P^T: A = Vt rows d = ct*32 + il, k-chunks h and h+2
#pragma unroll
      for (int ct = 0; ct < 8; ++ct) {
        int d0 = ct * 32 + il;
        int sw = (d0 >> 1) & 3;
        bf16x8 a0 = *(const bf16x8*)&Vb_[(d0 * 4 + (h ^ sw)) * 8];
        oacc[ct] = MFMA32(a0, pf0, oacc[ct]);
        bf16x8 a1 = *(const bf16x8*)&Vb_[(d0 * 4 + ((h + 2) ^ sw)) * 8];
        oacc[ct] = MFMA32(a1, pf1, oacc[ct]);
      }
    }
  }
#undef STAGE
  // write segment partials. g = slot for (ib, seg); ib = 4a+r blocks of 128.
  const int a_ = ib >> 2, r_ = ib & 3;
  const int g = 2 * a_ * (a_ + 1) + r_ * (a_ + 1) + seg;
  if (h == 0) {
    float* mlb = ml_out + ((size_t)g * 128 + 32 * w + il) * 2;
    mlb[0] = mrun;
    mlb[1] = lrun;
  }
  unsigned short* ab = acc_out + ((size_t)g * 128 + 32 * w + il) * DM;
#pragma unroll
  for (int ct = 0; ct < 8; ++ct)
#pragma unroll
    for (int tt = 0; tt < 4; ++tt) {
      // regs 4t..4t+3 -> d = ct*32 + 8t + 4h + 0..3 (8B store)
      unsigned int lo = (unsigned)f2bf_bits(oacc[ct][4 * tt + 0]) |
                        ((unsigned)f2bf_bits(oacc[ct][4 * tt + 1]) << 16);
      unsigned int hi = (unsigned)f2bf_bits(oacc[ct][4 * tt + 2]) |
                        ((unsigned)f2bf_bits(oacc[ct][4 * tt + 3]) << 16);
      *(uint2*)&ab[ct * 32 + 8 * tt + 4 * h] = make_uint2(lo, hi);
    }
}

// ---------------------------------------------------------------------------
// Kernel 3: combine segment partials. O = sum_s w_s*acc_s / sum_s w_s*l_s,
// w_s = 2^(m_s - M). grid 256 blocks x 256 thr; thread = (row, 32-col group).
// Row blocks are 128 rows; slots g0(ib) = 2a(a+1)+r(a+1), ns = a+1 (ib=4a+r).
// ---------------------------------------------------------------------------
__global__ __launch_bounds__(256) void combine_kernel(
    const float* __restrict__ ml, const unsigned short* __restrict__ pacc,
    float* __restrict__ out) {
  const int t = threadIdx.x;
  const int row = blockIdx.x * 32 + (t >> 3);
  const int cg = (t & 7) * 32;
  const int ib = row >> 7, rib = row & 127;
  const int a = ib >> 2, r = ib & 3;
  const int g0 = 2 * a * (a + 1) + r * (a + 1);
  const int ns = a + 1;
  float M = -1e30f;
  for (int s = 0; s < ns; ++s) M = fmaxf(M, ml[((size_t)(g0 + s) * 128 + rib) * 2]);
  float Wd = 0.f;
  float acc[32];
#pragma unroll
  for (int j = 0; j < 32; ++j) acc[j] = 0.f;
  for (int s = 0; s < ns; ++s) {
    const float* mls = ml + ((size_t)(g0 + s) * 128 + rib) * 2;
    float wv = exp2_fast(mls[0] - M);
    Wd += wv * mls[1];
    const unsigned short* pa = pacc + ((size_t)(g0 + s) * 128 + rib) * DM + cg;
#pragma unroll
    for (int v4 = 0; v4 < 4; ++v4) {
      bf16x8 b = *(const bf16x8*)(pa + v4 * 8);
#pragma unroll
      for (int j = 0; j < 8; ++j) acc[v4 * 8 + j] += wv * (float)b[j];
    }
  }
  float inv = 1.0f / Wd;
#pragma unroll
  for (int j = 0; j < 32; ++j) out[(size_t)row * DM + cg + j] = acc[j] * inv;
}

// ---------------------------------------------------------------------------
extern "C" void kernel_launch(void* const* d_in, const int* in_sizes, int n_in,
                              void* d_out, int out_size, void* d_ws, size_t ws_size,
                              hipStream_t stream) {
  const float* X  = (const float*)d_in[0];
  const float* Wq = (const float*)d_in[1];
  const float* Wk = (const float*)d_in[2];
  const float* Wv = (const float*)d_in[3];
  const void* mask = d_in[4];
  float* out = (float*)d_out;

  char* ws = (char*)d_ws;
  int* flag = (int*)ws;
  unsigned short* Qs = (unsigned short*)(ws + 4096);
  unsigned short* Kb = Qs + (size_t)NT * DM;
  unsigned short* Vt = Kb + (size_t)NT * DM;
  float* ml = (float*)(Vt + (size_t)NT * DM);                 // 544*128*2 f32
  unsigned short* pacc = (unsigned short*)(ml + (size_t)544 * 128 * 2);
  unsigned long long* bmw = (unsigned long long*)((char*)pacc + (size_t)544 * 128 * DM * 2);
  // total ws use: 4096 + 12 MiB + 544 KiB + 34 MiB + 8 MiB ~= 55 MiB

  detect_kernel<<<1, 256, 0, stream>>>((const unsigned int*)mask, flag);
  maskpack_kernel<<<2048, 256, 0, stream>>>(mask, flag, bmw);
  proj_kernel<<<dim3(128, 3), 256, 0, stream>>>(X, Wq, Wk, Wv, Qs, Kb, Vt);
  flash_kernel<<<dim3(64, 16), 256, 0, stream>>>(Qs, Kb, Vt, (const unsigned int*)bmw,
                                                 ml, pacc);
  combine_kernel<<<256, 256, 0, stream>>>(ml, pacc, out);
}